// Round 19
// baseline (84.580 us; speedup 1.0000x reference)
//
#include <hip/hip_runtime.h>
#include <hip/hip_bf16.h>

#define STUN   50000
#define BATCH  4096
#define LOG2E  1.4426950408889634f

__device__ __forceinline__ float fexp2(float x){ return __builtin_amdgcn_exp2f(x); }
__device__ __forceinline__ float frcp (float x){ return __builtin_amdgcn_rcpf(x); }
__device__ __forceinline__ float fsig (float x){ return frcp(1.0f + fexp2(-LOG2E * x)); }

// ---------------------------------------------------------------------------
// K0: transposes + E-matrix precompute. 960 blocks x 128 threads. (r12-proven)
// ---------------------------------------------------------------------------
__global__ __launch_bounds__(128) void k_pre(
    const float* __restrict__ kle,
    const float* __restrict__ W1,
    const float* __restrict__ W2,
    const float* __restrict__ fc1_W,
    const float* __restrict__ fc2_W,
    float* __restrict__ kleT,
    float* __restrict__ fc1T,
    float* __restrict__ fc2T,
    float* __restrict__ W1aT,
    float* __restrict__ W2aT,
    float* __restrict__ E1i,
    float* __restrict__ E2i)
{
    const int bid = blockIdx.x;
    const int t   = threadIdx.x;   // 0..127
    if (bid < 64) {
        const int u = bid;
        kleT[u * 128 + t] = kle[t * 64 + u];
    } else if (bid < 256) {
        const int u = bid - 64;
        fc1T[u * 128 + t] = fc1_W[t * 192 + u];
    } else if (bid < 448) {
        const int u = bid - 256;
        fc2T[u * 128 + t] = fc2_W[t * 192 + u];
    } else if (bid < 576) {
        const int u = bid - 448;
        W1aT[u * 128 + t] = W1[t * 192 + u];
    } else if (bid < 704) {
        const int u = bid - 576;
        W2aT[u * 128 + t] = W2[t * 192 + u];
    } else if (bid < 832) {
        const int j = bid - 704;          // lane t = k
        float acc = 0.f;
        #pragma unroll
        for (int u4 = 0; u4 < 16; ++u4) {
            const float4 kv = *(const float4*)&kle[t * 64 + u4 * 4];
            const float4 wv = *(const float4*)&W1[j * 192 + 128 + u4 * 4];
            acc += kv.x * wv.x + kv.y * wv.y + kv.z * wv.z + kv.w * wv.w;
        }
        E1i[((j >> 2) * 128 + t) * 4 + (j & 3)] = fexp2(-LOG2E * acc);
    } else {
        const int j = bid - 832;
        float acc = 0.f;
        #pragma unroll
        for (int u4 = 0; u4 < 16; ++u4) {
            const float4 kv = *(const float4*)&kle[t * 64 + u4 * 4];
            const float4 wv = *(const float4*)&W2[j * 192 + 128 + u4 * 4];
            acc += kv.x * wv.x + kv.y * wv.y + kv.z * wv.z + kv.w * wv.w;
        }
        E2i[((j >> 2) * 128 + t) * 4 + (j & 3)] = fexp2(-LOG2E * acc);
    }
}

// ---------------------------------------------------------------------------
// K_FUSED v12: BB=4, 512 threads, grid 1024, launch_bounds(512,8)
//   -> 4 blocks x 8 waves = 32 waves/CU (8/SIMD). LDS ~20.5 KB. VGPR cap 64.
// Prep: wave w -> half = w&1 (WAVE-uniform: no half-aliasing in LDS reads),
//   iqo = w>>1; lane l: ul = l>>3 (8-way u-split), iql = l&7, iq = iqo*8+iql.
//   Thread: a[4 c][4 b], float4 GSTEP (16 FMA / LDS read).
//   Combine over ul: shfl_xor 8,16,32; ul==0 lanes store.
// Main: k = t&127; g2 = t>>7 -> bh = g2&1 (b-pair), jq = g2>>1 (j-half).
//   2 b x 64 j per thread; red[2][4][128] combine (conflict-free).
// ---------------------------------------------------------------------------
__global__ __launch_bounds__(512, 8) void k_fused(
    const int*   __restrict__ stu_id,
    const int*   __restrict__ exer_id,
    const float* __restrict__ student_emb,   // (2*50000, 64) flat
    const float* __restrict__ prompt_stu,    // (50000, 64)
    const float* __restrict__ k_diff,        // (20000, 64)
    const float* __restrict__ s_exer,        // (2, 64)
    const float* __restrict__ kleT,          // (64,128)
    const float* __restrict__ fc1T,          // (192,128)
    const float* __restrict__ fc2T,
    const float* __restrict__ W1aT,          // (128,128)
    const float* __restrict__ W2aT,
    const float* __restrict__ fc1_b,
    const float* __restrict__ fc2_b,
    const float* __restrict__ E1i,           // [j4=32][k=128][4]
    const float* __restrict__ E2i,
    const float* __restrict__ W3,
    const float* __restrict__ b3,
    const float* __restrict__ kn,
    float* __restrict__ out)
{
    __shared__ __align__(16) float sh_in [4][64][4];    // 4 KB [src][u][b]
    __shared__ __align__(16) float sh_old[2][128][4];   // 4 KB [half][idx][b]
    __shared__ __align__(16) float sh_e  [2][128][4];   // 4 KB
    __shared__ __align__(16) float ses   [2][4][128];   // 4 KB [mat][b][j]
    __shared__ __align__(16) float red   [2][4][128];   // 4 KB [jq][b][k]
    __shared__ float r_o[4][2];
    __shared__ float r_k[4][2];

    const int t  = threadIdx.x;           // 0..511
    const int b0 = blockIdx.x * 4;

    // ---- gather: 128 threads per local b; sp splits sources ----
    {
        const int g   = t >> 7;
        const int sp  = (t >> 6) & 1;
        const int u   = t & 63;
        const int sid = stu_id[b0 + g];
        const int eid = exer_id[b0 + g];
        if (sp == 0) {
            sh_in[0][u][g] = student_emb[sid * 64 + u];
            sh_in[1][u][g] = fsig(k_diff[eid * 64 + u]);
        } else {
            const int er = (eid >= 10000) ? 1 : 0;
            sh_in[2][u][g] = prompt_stu[(sid % STUN) * 64 + u];
            sh_in[3][u][g] = fsig(s_exer[er * 64 + u]);
        }
    }
    __syncthreads();

    const int w    = t >> 6;              // wave 0..7
    const int half = w & 1;               // WAVE-uniform
    const int iqo  = w >> 1;              // 0..3
    const int l    = t & 63;
    const int ul   = l >> 3;              // u-split 0..7 (lane bits 3-5)
    const int iql  = l & 7;
    const int iq   = iqo * 8 + iql;       // 0..31 -> idx = iq*4+c

    float a[4][4];

#define CLR { _Pragma("unroll") for (int c = 0; c < 4; ++c) \
              _Pragma("unroll") for (int b = 0; b < 4; ++b) a[c][b] = 0.f; }

#define FMAC(c, wc) { \
    a[c][0] = fmaf(wc, x0.x, a[c][0]); a[c][1] = fmaf(wc, x0.y, a[c][1]); \
    a[c][2] = fmaf(wc, x0.z, a[c][2]); a[c][3] = fmaf(wc, x0.w, a[c][3]); }

#define GSTEP(wp, xp) { \
    const float4 w4 = *(const float4*)(wp); \
    const float4 x0 = *(const float4*)(xp); \
    FMAC(0, w4.x); FMAC(1, w4.y); FMAC(2, w4.z); FMAC(3, w4.w); }

#define COMBINE { _Pragma("unroll") for (int c = 0; c < 4; ++c) \
    _Pragma("unroll") for (int b = 0; b < 4; ++b) { \
        float v = a[c][b]; \
        v += __shfl_xor(v, 8); \
        v += __shfl_xor(v, 16); \
        v += __shfl_xor(v, 32); \
        a[c][b] = v; } }

    // ---- stage 1: old[idx] = sig( dot64(x_row, kle[idx]) ) ----
    CLR;
    #pragma unroll 4
    for (int s = 0; s < 8; ++s) {
        const int u = ul + s * 8;
        GSTEP(&kleT[u * 128 + iq * 4], &sh_in[half][u][0]);
    }
    COMBINE;
    if (ul == 0) {
        #pragma unroll
        for (int c = 0; c < 4; ++c)
            *(float4*)&sh_old[half][iq * 4 + c][0] =
                make_float4(fsig(a[c][0]), fsig(a[c][1]), fsig(a[c][2]), fsig(a[c][3]));
    }
    __syncthreads();

    // ---- stage 2: e[idx] = sig( [p, old] @ fcW[idx] + fcb[idx] ) ----
    CLR;
    {
        const float* fcT = half ? fc2T : fc1T;
        #pragma unroll 4
        for (int s = 0; s < 8; ++s) {
            const int u = ul + s * 8;
            GSTEP(&fcT[u * 128 + iq * 4], &sh_in[2 + half][u][0]);
        }
        #pragma unroll 4
        for (int s = 0; s < 16; ++s) {
            const int u = ul + s * 8;
            GSTEP(&fcT[(64 + u) * 128 + iq * 4], &sh_old[half][u][0]);
        }
    }
    COMBINE;
    if (ul == 0) {
        const float* fcb = half ? fc2_b : fc1_b;
        #pragma unroll
        for (int c = 0; c < 4; ++c) {
            const float bias = fcb[iq * 4 + c];
            *(float4*)&sh_e[half][iq * 4 + c][0] =
                make_float4(fsig(a[c][0] + bias), fsig(a[c][1] + bias),
                            fsig(a[c][2] + bias), fsig(a[c][3] + bias));
        }
    }
    __syncthreads();

    // ---- stage 3: ses[mat][b][j] = exp2( -log2e * dot128(e, Wa[j]) ) ----
    CLR;
    {
        const float* WT = half ? W2aT : W1aT;
        #pragma unroll 4
        for (int s = 0; s < 16; ++s) {
            const int u = ul + s * 8;
            GSTEP(&WT[u * 128 + iq * 4], &sh_e[half][u][0]);
        }
    }
    COMBINE;
    if (ul == 0) {
        #pragma unroll
        for (int c = 0; c < 4; ++c) {
            #pragma unroll
            for (int b = 0; b < 4; ++b)
                ses[half][b][iq * 4 + c] = fexp2(-LOG2E * a[c][b]);
        }
    }
#undef CLR
#undef FMAC
#undef GSTEP
#undef COMBINE
    __syncthreads();

    // ---- main loop: k = t&127; (bh, jq) = (g2&1, g2>>1); 2 b x 64 j ----
    const int k  = t & 127;
    const int g2 = t >> 7;                // 0..3
    const int bh = g2 & 1;
    const int jq = g2 >> 1;
    const int i0 = bh * 2;

    const float4* E1v = (const float4*)E1i + k;
    const float4* E2v = (const float4*)E2i + k;

    float acc0 = 0.f, acc1 = 0.f;

#define COMP(acc, esv1, esv2, e1c, e2c, w3c) { \
        const float uu = (esv1) * (e1c); \
        const float vv = (esv2) * (e2c); \
        const float dd = frcp((1.f + uu) * (1.f + vv)); \
        acc = fmaf((vv - uu) * dd, (w3c), acc); }

    #pragma unroll 4
    for (int i = 0; i < 16; ++i) {
        const int j4 = jq * 16 + i;
        const int j  = j4 * 4;
        const float4 e1  = E1v[j4 * 128];
        const float4 e2  = E2v[j4 * 128];
        const float4 w3  = *(const float4*)&W3[j];
        const float4 p1a = *(const float4*)&ses[0][i0 + 0][j];
        const float4 p2a = *(const float4*)&ses[1][i0 + 0][j];
        const float4 p1b = *(const float4*)&ses[0][i0 + 1][j];
        const float4 p2b = *(const float4*)&ses[1][i0 + 1][j];
        COMP(acc0, p1a.x, p2a.x, e1.x, e2.x, w3.x);
        COMP(acc0, p1a.y, p2a.y, e1.y, e2.y, w3.y);
        COMP(acc0, p1a.z, p2a.z, e1.z, e2.z, w3.z);
        COMP(acc0, p1a.w, p2a.w, e1.w, e2.w, w3.w);
        COMP(acc1, p1b.x, p2b.x, e1.x, e2.x, w3.x);
        COMP(acc1, p1b.y, p2b.y, e1.y, e2.y, w3.y);
        COMP(acc1, p1b.z, p2b.z, e1.z, e2.z, w3.z);
        COMP(acc1, p1b.w, p2b.w, e1.w, e2.w, w3.w);
    }
#undef COMP

    // ---- store j-half partials (lanes on k -> conflict-free) ----
    red[jq][i0 + 0][k] = acc0;
    red[jq][i0 + 1][k] = acc1;
    __syncthreads();

    // ---- combine halves + outer sigmoid + kn-weighted k-mean ----
    {
        const float bb3 = b3[0];
        const int b  = t >> 7;            // wave-uniform (b = w>>1)
        const int kk = t & 127;
        const float s  = red[0][b][kk] + red[1][b][kk];
        const float o  = fsig(s + bb3);
        const float kv = kn[(b0 + b) * 128 + kk];
        float co = o * kv, ck = kv;
        #pragma unroll
        for (int off = 1; off < 64; off <<= 1) {
            co += __shfl_xor(co, off);
            ck += __shfl_xor(ck, off);
        }
        if ((t & 63) == 0) {
            const int kh = w & 1;
            r_o[b][kh] = co;
            r_k[b][kh] = ck;
        }
    }
    __syncthreads();
    if (t < 4) {
        const float so = r_o[t][0] + r_o[t][1];
        const float sk = r_k[t][0] + r_k[t][1];
        out[b0 + t] = so / sk;
    }
}

// ---------------------------------------------------------------------------
extern "C" void kernel_launch(void* const* d_in, const int* in_sizes, int n_in,
                              void* d_out, int out_size, void* d_ws, size_t ws_size,
                              hipStream_t stream)
{
    const int*   stu_id      = (const int*)  d_in[0];
    const int*   exer_id     = (const int*)  d_in[1];
    const float* kn_emb      = (const float*)d_in[2];
    const float* student_emb = (const float*)d_in[3];
    const float* prompt_stu  = (const float*)d_in[4];
    const float* kle         = (const float*)d_in[5];
    const float* k_diff      = (const float*)d_in[6];
    const float* s_exer      = (const float*)d_in[7];
    const float* W1          = (const float*)d_in[8];
    const float* W2          = (const float*)d_in[9];
    const float* W3          = (const float*)d_in[10];
    const float* b3          = (const float*)d_in[11];
    const float* fc1_W       = (const float*)d_in[12];
    const float* fc1_b       = (const float*)d_in[13];
    const float* fc2_W       = (const float*)d_in[14];
    const float* fc2_b       = (const float*)d_in[15];
    float* out = (float*)d_out;

    float* ws   = (float*)d_ws;
    float* kleT = ws;                        // 64*128   = 8192
    float* fc1T = kleT + 8192;               // 192*128  = 24576
    float* fc2T = fc1T + 24576;
    float* W1aT = fc2T + 24576;              // 128*128  = 16384
    float* W2aT = W1aT + 16384;
    float* E1i  = W2aT + 16384;              // 128*128  = 16384
    float* E2i  = E1i  + 16384;

    k_pre  <<<960, 128, 0, stream>>>(kle, W1, W2, fc1_W, fc2_W,
                                     kleT, fc1T, fc2T, W1aT, W2aT, E1i, E2i);
    k_fused<<<BATCH / 4, 512, 0, stream>>>(stu_id, exer_id, student_emb, prompt_stu,
                                           k_diff, s_exer, kleT, fc1T, fc2T,
                                           W1aT, W2aT, fc1_b, fc2_b,
                                           E1i, E2i, W3, b3, kn_emb, out);
}

// Round 20
// 57.065 us; speedup vs baseline: 1.4822x; 1.4822x over previous
//
#include <hip/hip_runtime.h>
#include <hip/hip_bf16.h>

#define STUN   50000
#define BATCH  4096
#define LOG2E  1.4426950408889634f

__device__ __forceinline__ float fexp2(float x){ return __builtin_amdgcn_exp2f(x); }
__device__ __forceinline__ float frcp (float x){ return __builtin_amdgcn_rcpf(x); }
__device__ __forceinline__ float fsig (float x){ return frcp(1.0f + fexp2(-LOG2E * x)); }

// ---------------------------------------------------------------------------
// K0: transposes + E-matrix precompute. 960 blocks x 128 threads. (r12-proven)
// ---------------------------------------------------------------------------
__global__ __launch_bounds__(128) void k_pre(
    const float* __restrict__ kle,
    const float* __restrict__ W1,
    const float* __restrict__ W2,
    const float* __restrict__ fc1_W,
    const float* __restrict__ fc2_W,
    float* __restrict__ kleT,
    float* __restrict__ fc1T,
    float* __restrict__ fc2T,
    float* __restrict__ W1aT,
    float* __restrict__ W2aT,
    float* __restrict__ E1i,
    float* __restrict__ E2i)
{
    const int bid = blockIdx.x;
    const int t   = threadIdx.x;   // 0..127
    if (bid < 64) {
        const int u = bid;
        kleT[u * 128 + t] = kle[t * 64 + u];
    } else if (bid < 256) {
        const int u = bid - 64;
        fc1T[u * 128 + t] = fc1_W[t * 192 + u];
    } else if (bid < 448) {
        const int u = bid - 256;
        fc2T[u * 128 + t] = fc2_W[t * 192 + u];
    } else if (bid < 576) {
        const int u = bid - 448;
        W1aT[u * 128 + t] = W1[t * 192 + u];
    } else if (bid < 704) {
        const int u = bid - 576;
        W2aT[u * 128 + t] = W2[t * 192 + u];
    } else if (bid < 832) {
        const int j = bid - 704;          // lane t = k
        float acc = 0.f;
        #pragma unroll
        for (int u4 = 0; u4 < 16; ++u4) {
            const float4 kv = *(const float4*)&kle[t * 64 + u4 * 4];
            const float4 wv = *(const float4*)&W1[j * 192 + 128 + u4 * 4];
            acc += kv.x * wv.x + kv.y * wv.y + kv.z * wv.z + kv.w * wv.w;
        }
        E1i[((j >> 2) * 128 + t) * 4 + (j & 3)] = fexp2(-LOG2E * acc);
    } else {
        const int j = bid - 832;
        float acc = 0.f;
        #pragma unroll
        for (int u4 = 0; u4 < 16; ++u4) {
            const float4 kv = *(const float4*)&kle[t * 64 + u4 * 4];
            const float4 wv = *(const float4*)&W2[j * 192 + 128 + u4 * 4];
            acc += kv.x * wv.x + kv.y * wv.y + kv.z * wv.z + kv.w * wv.w;
        }
        E2i[((j >> 2) * 128 + t) * 4 + (j & 3)] = fexp2(-LOG2E * acc);
    }
}

// ---------------------------------------------------------------------------
// K_FUSED v13 = r19 with launch_bounds(512,6): VGPR cap ~85 (no-spill regime),
// 3 blocks/CU x 8 waves = 24 waves/CU (6/SIMD), 1.5x r13's TLP.
// Prep: wave w -> half = w&1 (WAVE-uniform), iqo = w>>1; lane l: ul = l>>3
//   (8-way u-split), iql = l&7, iq = iqo*8+iql. a[4 c][4 b], float4 GSTEP.
//   Combine over ul: shfl_xor 8,16,32; ul==0 lanes store.
// Main: k = t&127; g2 = t>>7 -> bh = g2&1 (b-pair), jq = g2>>1 (j-half).
//   2 b x 64 j per thread; red[2][4][128] combine (conflict-free).
// ---------------------------------------------------------------------------
__global__ __launch_bounds__(512, 6) void k_fused(
    const int*   __restrict__ stu_id,
    const int*   __restrict__ exer_id,
    const float* __restrict__ student_emb,   // (2*50000, 64) flat
    const float* __restrict__ prompt_stu,    // (50000, 64)
    const float* __restrict__ k_diff,        // (20000, 64)
    const float* __restrict__ s_exer,        // (2, 64)
    const float* __restrict__ kleT,          // (64,128)
    const float* __restrict__ fc1T,          // (192,128)
    const float* __restrict__ fc2T,
    const float* __restrict__ W1aT,          // (128,128)
    const float* __restrict__ W2aT,
    const float* __restrict__ fc1_b,
    const float* __restrict__ fc2_b,
    const float* __restrict__ E1i,           // [j4=32][k=128][4]
    const float* __restrict__ E2i,
    const float* __restrict__ W3,
    const float* __restrict__ b3,
    const float* __restrict__ kn,
    float* __restrict__ out)
{
    __shared__ __align__(16) float sh_in [4][64][4];    // 4 KB [src][u][b]
    __shared__ __align__(16) float sh_old[2][128][4];   // 4 KB [half][idx][b]
    __shared__ __align__(16) float sh_e  [2][128][4];   // 4 KB
    __shared__ __align__(16) float ses   [2][4][128];   // 4 KB [mat][b][j]
    __shared__ __align__(16) float red   [2][4][128];   // 4 KB [jq][b][k]
    __shared__ float r_o[4][2];
    __shared__ float r_k[4][2];

    const int t  = threadIdx.x;           // 0..511
    const int b0 = blockIdx.x * 4;

    // ---- gather: 128 threads per local b; sp splits sources ----
    {
        const int g   = t >> 7;
        const int sp  = (t >> 6) & 1;
        const int u   = t & 63;
        const int sid = stu_id[b0 + g];
        const int eid = exer_id[b0 + g];
        if (sp == 0) {
            sh_in[0][u][g] = student_emb[sid * 64 + u];
            sh_in[1][u][g] = fsig(k_diff[eid * 64 + u]);
        } else {
            const int er = (eid >= 10000) ? 1 : 0;
            sh_in[2][u][g] = prompt_stu[(sid % STUN) * 64 + u];
            sh_in[3][u][g] = fsig(s_exer[er * 64 + u]);
        }
    }
    __syncthreads();

    const int w    = t >> 6;              // wave 0..7
    const int half = w & 1;               // WAVE-uniform
    const int iqo  = w >> 1;              // 0..3
    const int l    = t & 63;
    const int ul   = l >> 3;              // u-split 0..7 (lane bits 3-5)
    const int iql  = l & 7;
    const int iq   = iqo * 8 + iql;       // 0..31 -> idx = iq*4+c

    float a[4][4];

#define CLR { _Pragma("unroll") for (int c = 0; c < 4; ++c) \
              _Pragma("unroll") for (int b = 0; b < 4; ++b) a[c][b] = 0.f; }

#define FMAC(c, wc) { \
    a[c][0] = fmaf(wc, x0.x, a[c][0]); a[c][1] = fmaf(wc, x0.y, a[c][1]); \
    a[c][2] = fmaf(wc, x0.z, a[c][2]); a[c][3] = fmaf(wc, x0.w, a[c][3]); }

#define GSTEP(wp, xp) { \
    const float4 w4 = *(const float4*)(wp); \
    const float4 x0 = *(const float4*)(xp); \
    FMAC(0, w4.x); FMAC(1, w4.y); FMAC(2, w4.z); FMAC(3, w4.w); }

#define COMBINE { _Pragma("unroll") for (int c = 0; c < 4; ++c) \
    _Pragma("unroll") for (int b = 0; b < 4; ++b) { \
        float v = a[c][b]; \
        v += __shfl_xor(v, 8); \
        v += __shfl_xor(v, 16); \
        v += __shfl_xor(v, 32); \
        a[c][b] = v; } }

    // ---- stage 1: old[idx] = sig( dot64(x_row, kle[idx]) ) ----
    CLR;
    #pragma unroll 4
    for (int s = 0; s < 8; ++s) {
        const int u = ul + s * 8;
        GSTEP(&kleT[u * 128 + iq * 4], &sh_in[half][u][0]);
    }
    COMBINE;
    if (ul == 0) {
        #pragma unroll
        for (int c = 0; c < 4; ++c)
            *(float4*)&sh_old[half][iq * 4 + c][0] =
                make_float4(fsig(a[c][0]), fsig(a[c][1]), fsig(a[c][2]), fsig(a[c][3]));
    }
    __syncthreads();

    // ---- stage 2: e[idx] = sig( [p, old] @ fcW[idx] + fcb[idx] ) ----
    CLR;
    {
        const float* fcT = half ? fc2T : fc1T;
        #pragma unroll 4
        for (int s = 0; s < 8; ++s) {
            const int u = ul + s * 8;
            GSTEP(&fcT[u * 128 + iq * 4], &sh_in[2 + half][u][0]);
        }
        #pragma unroll 4
        for (int s = 0; s < 16; ++s) {
            const int u = ul + s * 8;
            GSTEP(&fcT[(64 + u) * 128 + iq * 4], &sh_old[half][u][0]);
        }
    }
    COMBINE;
    if (ul == 0) {
        const float* fcb = half ? fc2_b : fc1_b;
        #pragma unroll
        for (int c = 0; c < 4; ++c) {
            const float bias = fcb[iq * 4 + c];
            *(float4*)&sh_e[half][iq * 4 + c][0] =
                make_float4(fsig(a[c][0] + bias), fsig(a[c][1] + bias),
                            fsig(a[c][2] + bias), fsig(a[c][3] + bias));
        }
    }
    __syncthreads();

    // ---- stage 3: ses[mat][b][j] = exp2( -log2e * dot128(e, Wa[j]) ) ----
    CLR;
    {
        const float* WT = half ? W2aT : W1aT;
        #pragma unroll 4
        for (int s = 0; s < 16; ++s) {
            const int u = ul + s * 8;
            GSTEP(&WT[u * 128 + iq * 4], &sh_e[half][u][0]);
        }
    }
    COMBINE;
    if (ul == 0) {
        #pragma unroll
        for (int c = 0; c < 4; ++c) {
            #pragma unroll
            for (int b = 0; b < 4; ++b)
                ses[half][b][iq * 4 + c] = fexp2(-LOG2E * a[c][b]);
        }
    }
#undef CLR
#undef FMAC
#undef GSTEP
#undef COMBINE
    __syncthreads();

    // ---- main loop: k = t&127; (bh, jq) = (g2&1, g2>>1); 2 b x 64 j ----
    const int k  = t & 127;
    const int g2 = t >> 7;                // 0..3
    const int bh = g2 & 1;
    const int jq = g2 >> 1;
    const int i0 = bh * 2;

    const float4* E1v = (const float4*)E1i + k;
    const float4* E2v = (const float4*)E2i + k;

    float acc0 = 0.f, acc1 = 0.f;

#define COMP(acc, esv1, esv2, e1c, e2c, w3c) { \
        const float uu = (esv1) * (e1c); \
        const float vv = (esv2) * (e2c); \
        const float dd = frcp((1.f + uu) * (1.f + vv)); \
        acc = fmaf((vv - uu) * dd, (w3c), acc); }

    #pragma unroll 4
    for (int i = 0; i < 16; ++i) {
        const int j4 = jq * 16 + i;
        const int j  = j4 * 4;
        const float4 e1  = E1v[j4 * 128];
        const float4 e2  = E2v[j4 * 128];
        const float4 w3  = *(const float4*)&W3[j];
        const float4 p1a = *(const float4*)&ses[0][i0 + 0][j];
        const float4 p2a = *(const float4*)&ses[1][i0 + 0][j];
        const float4 p1b = *(const float4*)&ses[0][i0 + 1][j];
        const float4 p2b = *(const float4*)&ses[1][i0 + 1][j];
        COMP(acc0, p1a.x, p2a.x, e1.x, e2.x, w3.x);
        COMP(acc0, p1a.y, p2a.y, e1.y, e2.y, w3.y);
        COMP(acc0, p1a.z, p2a.z, e1.z, e2.z, w3.z);
        COMP(acc0, p1a.w, p2a.w, e1.w, e2.w, w3.w);
        COMP(acc1, p1b.x, p2b.x, e1.x, e2.x, w3.x);
        COMP(acc1, p1b.y, p2b.y, e1.y, e2.y, w3.y);
        COMP(acc1, p1b.z, p2b.z, e1.z, e2.z, w3.z);
        COMP(acc1, p1b.w, p2b.w, e1.w, e2.w, w3.w);
    }
#undef COMP

    // ---- store j-half partials (lanes on k -> conflict-free) ----
    red[jq][i0 + 0][k] = acc0;
    red[jq][i0 + 1][k] = acc1;
    __syncthreads();

    // ---- combine halves + outer sigmoid + kn-weighted k-mean ----
    {
        const float bb3 = b3[0];
        const int b  = t >> 7;            // wave-uniform (b = w>>1)
        const int kk = t & 127;
        const float s  = red[0][b][kk] + red[1][b][kk];
        const float o  = fsig(s + bb3);
        const float kv = kn[(b0 + b) * 128 + kk];
        float co = o * kv, ck = kv;
        #pragma unroll
        for (int off = 1; off < 64; off <<= 1) {
            co += __shfl_xor(co, off);
            ck += __shfl_xor(ck, off);
        }
        if ((t & 63) == 0) {
            const int kh = w & 1;
            r_o[b][kh] = co;
            r_k[b][kh] = ck;
        }
    }
    __syncthreads();
    if (t < 4) {
        const float so = r_o[t][0] + r_o[t][1];
        const float sk = r_k[t][0] + r_k[t][1];
        out[b0 + t] = so / sk;
    }
}

// ---------------------------------------------------------------------------
extern "C" void kernel_launch(void* const* d_in, const int* in_sizes, int n_in,
                              void* d_out, int out_size, void* d_ws, size_t ws_size,
                              hipStream_t stream)
{
    const int*   stu_id      = (const int*)  d_in[0];
    const int*   exer_id     = (const int*)  d_in[1];
    const float* kn_emb      = (const float*)d_in[2];
    const float* student_emb = (const float*)d_in[3];
    const float* prompt_stu  = (const float*)d_in[4];
    const float* kle         = (const float*)d_in[5];
    const float* k_diff      = (const float*)d_in[6];
    const float* s_exer      = (const float*)d_in[7];
    const float* W1          = (const float*)d_in[8];
    const float* W2          = (const float*)d_in[9];
    const float* W3          = (const float*)d_in[10];
    const float* b3          = (const float*)d_in[11];
    const float* fc1_W       = (const float*)d_in[12];
    const float* fc1_b       = (const float*)d_in[13];
    const float* fc2_W       = (const float*)d_in[14];
    const float* fc2_b       = (const float*)d_in[15];
    float* out = (float*)d_out;

    float* ws   = (float*)d_ws;
    float* kleT = ws;                        // 64*128   = 8192
    float* fc1T = kleT + 8192;               // 192*128  = 24576
    float* fc2T = fc1T + 24576;
    float* W1aT = fc2T + 24576;              // 128*128  = 16384
    float* W2aT = W1aT + 16384;
    float* E1i  = W2aT + 16384;              // 128*128  = 16384
    float* E2i  = E1i  + 16384;

    k_pre  <<<960, 128, 0, stream>>>(kle, W1, W2, fc1_W, fc2_W,
                                     kleT, fc1T, fc2T, W1aT, W2aT, E1i, E2i);
    k_fused<<<BATCH / 4, 512, 0, stream>>>(stu_id, exer_id, student_emb, prompt_stu,
                                           k_diff, s_exer, kleT, fc1T, fc2T,
                                           W1aT, W2aT, fc1_b, fc2_b,
                                           E1i, E2i, W3, b3, kn_emb, out);
}

// Round 21
// 46.434 us; speedup vs baseline: 1.8215x; 1.2289x over previous
//
#include <hip/hip_runtime.h>
#include <hip/hip_bf16.h>

#define STUN   50000
#define BATCH  4096
#define LOG2E  1.4426950408889634f

__device__ __forceinline__ float fexp2(float x){ return __builtin_amdgcn_exp2f(x); }
__device__ __forceinline__ float frcp (float x){ return __builtin_amdgcn_rcpf(x); }
__device__ __forceinline__ float fsig (float x){ return frcp(1.0f + fexp2(-LOG2E * x)); }

// ---------------------------------------------------------------------------
// K0: transposes + E-matrix precompute. 960 blocks x 128 threads. (r12-proven)
//   kleT  [u=64][idx=128]  = kle[idx][u]
//   fc1T/fc2T [u=192][128] = fcW[idx][u]
//   W1aT/W2aT [u=128][128] = W[idx][u]          (the 'a' half, u<128)
//   E1i/E2i [j4=32][k=128][4] = exp2(-log2e * sum_t kle[k][t]*W[j4*4+c][128+t])
// ---------------------------------------------------------------------------
__global__ __launch_bounds__(128) void k_pre(
    const float* __restrict__ kle,
    const float* __restrict__ W1,
    const float* __restrict__ W2,
    const float* __restrict__ fc1_W,
    const float* __restrict__ fc2_W,
    float* __restrict__ kleT,
    float* __restrict__ fc1T,
    float* __restrict__ fc2T,
    float* __restrict__ W1aT,
    float* __restrict__ W2aT,
    float* __restrict__ E1i,
    float* __restrict__ E2i)
{
    const int bid = blockIdx.x;
    const int t   = threadIdx.x;   // 0..127
    if (bid < 64) {
        const int u = bid;
        kleT[u * 128 + t] = kle[t * 64 + u];
    } else if (bid < 256) {
        const int u = bid - 64;
        fc1T[u * 128 + t] = fc1_W[t * 192 + u];
    } else if (bid < 448) {
        const int u = bid - 256;
        fc2T[u * 128 + t] = fc2_W[t * 192 + u];
    } else if (bid < 576) {
        const int u = bid - 448;
        W1aT[u * 128 + t] = W1[t * 192 + u];
    } else if (bid < 704) {
        const int u = bid - 576;
        W2aT[u * 128 + t] = W2[t * 192 + u];
    } else if (bid < 832) {
        const int j = bid - 704;          // lane t = k
        float acc = 0.f;
        #pragma unroll
        for (int u4 = 0; u4 < 16; ++u4) {
            const float4 kv = *(const float4*)&kle[t * 64 + u4 * 4];
            const float4 wv = *(const float4*)&W1[j * 192 + 128 + u4 * 4];
            acc += kv.x * wv.x + kv.y * wv.y + kv.z * wv.z + kv.w * wv.w;
        }
        E1i[((j >> 2) * 128 + t) * 4 + (j & 3)] = fexp2(-LOG2E * acc);
    } else {
        const int j = bid - 832;
        float acc = 0.f;
        #pragma unroll
        for (int u4 = 0; u4 < 16; ++u4) {
            const float4 kv = *(const float4*)&kle[t * 64 + u4 * 4];
            const float4 wv = *(const float4*)&W2[j * 192 + 128 + u4 * 4];
            acc += kv.x * wv.x + kv.y * wv.y + kv.z * wv.z + kv.w * wv.w;
        }
        E2i[((j >> 2) * 128 + t) * 4 + (j & 3)] = fexp2(-LOG2E * acc);
    }
}

// ---------------------------------------------------------------------------
// K_FUSED (r13-best): idx-blocked prep (BBP=4) + LDS-es + E-from-L2 main.
// 4 batch elems/block, 256 threads, grid 1024 -> 4 blocks/CU (LDS ~37 KB).
// Prep: wave wv = u-quarter; lane: half=l>>5, iq=l&31 (4 idx each).
//       Partials via ps[]; combine thread (ch,cidx); es -> LDS ses.
// Main: t -> k=t&127, bh=t>>7 (b-pair); thread: 2 b x 128 j x 1 k.
//       u = es1*E1, v = es2*E2, acc += (v-u)*rcp((1+u)(1+v))*w3.
// ---------------------------------------------------------------------------
__global__ __launch_bounds__(256, 4) void k_fused(
    const int*   __restrict__ stu_id,
    const int*   __restrict__ exer_id,
    const float* __restrict__ student_emb,   // (2*50000, 64) flat
    const float* __restrict__ prompt_stu,    // (50000, 64)
    const float* __restrict__ k_diff,        // (20000, 64)
    const float* __restrict__ s_exer,        // (2, 64)
    const float* __restrict__ kleT,          // (64,128)
    const float* __restrict__ fc1T,          // (192,128)
    const float* __restrict__ fc2T,
    const float* __restrict__ W1aT,          // (128,128)
    const float* __restrict__ W2aT,
    const float* __restrict__ fc1_b,
    const float* __restrict__ fc2_b,
    const float* __restrict__ E1i,           // [j4=32][k=128][4]
    const float* __restrict__ E2i,
    const float* __restrict__ W3,
    const float* __restrict__ b3,
    const float* __restrict__ kn,
    float* __restrict__ out)
{
    __shared__ __align__(16) float sh_in [4][64][4];    //  4 KB [src][u][b]
    __shared__ __align__(16) float sh_old[2][128][4];   //  4 KB
    __shared__ __align__(16) float sh_e  [2][128][4];   //  4 KB
    __shared__ __align__(16) float ps[4][2][32][20];    // 20 KB [ug][half][iq][b*4+c]
    __shared__ __align__(16) float ses[2][4][128];      //  4 KB [mat][b][j]
    __shared__ float r_o[4][2];
    __shared__ float r_k[4][2];

    const int t  = threadIdx.x;           // 0..255
    const int b0 = blockIdx.x * 4;

    // ---- gather: 64 threads per local batch elem, coalesced ----
    {
        const int g   = t >> 6;
        const int u   = t & 63;
        const int sid = stu_id[b0 + g];
        const int eid = exer_id[b0 + g];
        const int er  = (eid >= 10000) ? 1 : 0;
        sh_in[0][u][g] = student_emb[sid * 64 + u];
        sh_in[1][u][g] = fsig(k_diff[eid * 64 + u]);
        sh_in[2][u][g] = prompt_stu[(sid % STUN) * 64 + u];
        sh_in[3][u][g] = fsig(s_exer[er * 64 + u]);
    }
    __syncthreads();

    const int wv   = t >> 6;              // u-quarter (wave id)
    const int l    = t & 63;
    const int half = l >> 5;
    const int iq   = l & 31;              // idx quad base: idx = iq*4+c
    float* myps = &ps[wv][half][iq][0];

    // combine-phase mapping (all 256 threads)
    const int ch   = t >> 7;
    const int cidx = t & 127;
    const int ciq  = cidx >> 2;
    const int cc   = cidx & 3;

    float a[4][4];

#define CLR { _Pragma("unroll") for (int c = 0; c < 4; ++c) \
              _Pragma("unroll") for (int b = 0; b < 4; ++b) a[c][b] = 0.f; }

#define FMAC(c, wc) { \
    a[c][0] = fmaf(wc, x0.x, a[c][0]); a[c][1] = fmaf(wc, x0.y, a[c][1]); \
    a[c][2] = fmaf(wc, x0.z, a[c][2]); a[c][3] = fmaf(wc, x0.w, a[c][3]); }

#define GSTEP(wp, xp) { \
    const float4 w4 = *(const float4*)(wp); \
    const float4 x0 = *(const float4*)&(xp)[0]; \
    FMAC(0, w4.x); FMAC(1, w4.y); FMAC(2, w4.z); FMAC(3, w4.w); }

#define PSTORE { _Pragma("unroll") for (int b = 0; b < 4; ++b) \
    *(float4*)&myps[b * 4] = make_float4(a[0][b], a[1][b], a[2][b], a[3][b]); }

#define PCOMB(res) float res[4]; \
    _Pragma("unroll") for (int b = 0; b < 4; ++b) \
        res[b] = ps[0][ch][ciq][b * 4 + cc] + ps[1][ch][ciq][b * 4 + cc] \
               + ps[2][ch][ciq][b * 4 + cc] + ps[3][ch][ciq][b * 4 + cc];

    // ---- stage 1: old[idx] = sig( dot64(x_row, kle[idx]) ) ----
    CLR;
    {
        const int u0 = wv * 16;
        #pragma unroll 4
        for (int u = u0; u < u0 + 16; ++u)
            GSTEP(&kleT[u * 128 + iq * 4], sh_in[half][u]);
    }
    PSTORE;
    __syncthreads();
    {
        PCOMB(s);
        #pragma unroll
        for (int b = 0; b < 4; ++b) sh_old[ch][cidx][b] = fsig(s[b]);
    }
    __syncthreads();

    // ---- stage 2: e[idx] = sig( [p, old] @ fcW[idx] + fcb[idx] ) ----
    CLR;
    {
        const float* fcT = half ? fc2T : fc1T;
        const int u0 = wv * 48;
        const int ue_in = (u0 + 48 < 64) ? u0 + 48 : 64;
        #pragma unroll 4
        for (int u = u0; u < ue_in; ++u)
            GSTEP(&fcT[u * 128 + iq * 4], sh_in[2 + half][u]);
        const int us_old = (u0 > 64) ? u0 : 64;
        #pragma unroll 4
        for (int u = us_old; u < u0 + 48; ++u)
            GSTEP(&fcT[u * 128 + iq * 4], sh_old[half][u - 64]);
    }
    PSTORE;
    __syncthreads();
    {
        PCOMB(s);
        const float bias = (ch ? fc2_b : fc1_b)[cidx];
        #pragma unroll
        for (int b = 0; b < 4; ++b) sh_e[ch][cidx][b] = fsig(s[b] + bias);
    }
    __syncthreads();

    // ---- stage 3: ses[mat][b][idx] = exp2( -log2e * dot128(e, Wa[idx]) ) ----
    CLR;
    {
        const float* WT = half ? W2aT : W1aT;
        const int u0 = wv * 32;
        #pragma unroll 4
        for (int u = u0; u < u0 + 32; ++u)
            GSTEP(&WT[u * 128 + iq * 4], sh_e[half][u]);
    }
    PSTORE;
    __syncthreads();
    {
        PCOMB(s);
        #pragma unroll
        for (int b = 0; b < 4; ++b)
            ses[ch][b][cidx] = fexp2(-LOG2E * s[b]);
    }
#undef CLR
#undef FMAC
#undef GSTEP
#undef PSTORE
#undef PCOMB
    __syncthreads();

    // ---- main loop: t -> k = t&127, bh = t>>7; 2 b x 128 j ----
    const int k  = t & 127;
    const int bh = t >> 7;
    const int i0 = bh * 2;

    const float4* E1v = (const float4*)E1i + k;
    const float4* E2v = (const float4*)E2i + k;

    float acc0 = 0.f, acc1 = 0.f;

#define COMP(acc, esv1, esv2, e1c, e2c, w3c) { \
        const float uu = (esv1) * (e1c); \
        const float vv = (esv2) * (e2c); \
        const float dd = frcp((1.f + uu) * (1.f + vv)); \
        acc = fmaf((vv - uu) * dd, (w3c), acc); }

    #pragma unroll 4
    for (int j4 = 0; j4 < 32; ++j4) {
        const int j = j4 * 4;
        const float4 e1  = E1v[j4 * 128];
        const float4 e2  = E2v[j4 * 128];
        const float4 w3  = *(const float4*)&W3[j];
        const float4 p1a = *(const float4*)&ses[0][i0 + 0][j];
        const float4 p2a = *(const float4*)&ses[1][i0 + 0][j];
        const float4 p1b = *(const float4*)&ses[0][i0 + 1][j];
        const float4 p2b = *(const float4*)&ses[1][i0 + 1][j];
        COMP(acc0, p1a.x, p2a.x, e1.x, e2.x, w3.x);
        COMP(acc0, p1a.y, p2a.y, e1.y, e2.y, w3.y);
        COMP(acc0, p1a.z, p2a.z, e1.z, e2.z, w3.z);
        COMP(acc0, p1a.w, p2a.w, e1.w, e2.w, w3.w);
        COMP(acc1, p1b.x, p2b.x, e1.x, e2.x, w3.x);
        COMP(acc1, p1b.y, p2b.y, e1.y, e2.y, w3.y);
        COMP(acc1, p1b.z, p2b.z, e1.z, e2.z, w3.z);
        COMP(acc1, p1b.w, p2b.w, e1.w, e2.w, w3.w);
    }
#undef COMP

    // ---- epilogue: outer sigmoid + kn-weighted mean over k ----
    const float bb3 = b3[0];
    const float o0  = fsig(acc0 + bb3);
    const float o1  = fsig(acc1 + bb3);
    const float kn0 = kn[(b0 + i0 + 0) * 128 + k];
    const float kn1 = kn[(b0 + i0 + 1) * 128 + k];
    float co0 = o0 * kn0, ck0 = kn0;
    float co1 = o1 * kn1, ck1 = kn1;
    #pragma unroll
    for (int off = 1; off < 64; off <<= 1) {
        co0 += __shfl_xor(co0, off);
        ck0 += __shfl_xor(ck0, off);
        co1 += __shfl_xor(co1, off);
        ck1 += __shfl_xor(ck1, off);
    }
    const int w = t >> 6;
    if ((t & 63) == 0) {
        r_o[w][0] = co0; r_o[w][1] = co1;
        r_k[w][0] = ck0; r_k[w][1] = ck1;
    }
    __syncthreads();
    if (t < 4) {
        const int bhh = t >> 1;           // b-pair
        const int i   = t & 1;
        const float so = r_o[bhh * 2][i] + r_o[bhh * 2 + 1][i];
        const float sk = r_k[bhh * 2][i] + r_k[bhh * 2 + 1][i];
        out[b0 + bhh * 2 + i] = so / sk;
    }
}

// ---------------------------------------------------------------------------
extern "C" void kernel_launch(void* const* d_in, const int* in_sizes, int n_in,
                              void* d_out, int out_size, void* d_ws, size_t ws_size,
                              hipStream_t stream)
{
    const int*   stu_id      = (const int*)  d_in[0];
    const int*   exer_id     = (const int*)  d_in[1];
    const float* kn_emb      = (const float*)d_in[2];
    const float* student_emb = (const float*)d_in[3];
    const float* prompt_stu  = (const float*)d_in[4];
    const float* kle         = (const float*)d_in[5];
    const float* k_diff      = (const float*)d_in[6];
    const float* s_exer      = (const float*)d_in[7];
    const float* W1          = (const float*)d_in[8];
    const float* W2          = (const float*)d_in[9];
    const float* W3          = (const float*)d_in[10];
    const float* b3          = (const float*)d_in[11];
    const float* fc1_W       = (const float*)d_in[12];
    const float* fc1_b       = (const float*)d_in[13];
    const float* fc2_W       = (const float*)d_in[14];
    const float* fc2_b       = (const float*)d_in[15];
    float* out = (float*)d_out;

    float* ws   = (float*)d_ws;
    float* kleT = ws;                        // 64*128   = 8192
    float* fc1T = kleT + 8192;               // 192*128  = 24576
    float* fc2T = fc1T + 24576;
    float* W1aT = fc2T + 24576;              // 128*128  = 16384
    float* W2aT = W1aT + 16384;
    float* E1i  = W2aT + 16384;              // 128*128  = 16384
    float* E2i  = E1i  + 16384;

    k_pre  <<<960, 128, 0, stream>>>(kle, W1, W2, fc1_W, fc2_W,
                                     kleT, fc1T, fc2T, W1aT, W2aT, E1i, E2i);
    k_fused<<<BATCH / 4, 256, 0, stream>>>(stu_id, exer_id, student_emb, prompt_stu,
                                           k_diff, s_exer, kleT, fc1T, fc2T,
                                           W1aT, W2aT, fc1_b, fc2_b,
                                           E1i, E2i, W3, b3, kn_emb, out);
}